// Round 5
// baseline (175.436 us; speedup 1.0000x reference)
//
#include <hip/hip_runtime.h>
#include <hip/hip_bf16.h>
#include <stdint.h>

// LoRAExpert: out = ragged_dot(x, W, groups) + scale[a] * ((x @ A[a,e]) @ B[a,e])
// T=8192, D_IN=D_OUT=1024, E=8 (equal groups of 1024), A=4 adapters, R=16.
// Inputs fp32, output fp32. ws = 256 MiB.
//
// Round 10: kill the xp intermediate (R9 post-mortem: xva time tracks BYTES,
// not barrier count; 75% of its traffic was the xp pack round-trip).
//   k_prepA : lora_A -> Aoct (scale folded). 256 blocks. (unchanged)
//   k_pv    : blocks [0,512)    : V-only (R9 xva minus xp stores): x fp32 ->
//                                 bf16 in-reg, V = x@Aoct[e], adapter-masked
//                                 -> vs[8192][64] bf16 (1 MB). XCD-swizzled so
//                                 xcd k serves expert k (Aoct L2-resident).
//             blocks [512,1600) : W/lora_B -> Boct pack (unchanged).
//   k_gemm2 : out = [x|V](K=1088) @ Boct[e]. A-tile kt=0..15 is REG-STAGED
//             from x fp32 (cvt + XOR-swizzled ds_write, same layout the
//             fragment reads expect); kt=16 stages the V slice via gload_lds.
//             With the XCD swizzle each XCD's x slice is 4 MB = L2-resident,
//             so the 8x re-read of x is L2 traffic, not HBM.

#define T_TOK 8192
#define DIN   1024
#define DOUT  1024
#define NE    8
#define NA    4
#define RK    16
#define NOCT  136       // 128 (W) + 8 (lora_B) K-octs

typedef __attribute__((ext_vector_type(8))) short short8;
typedef __attribute__((ext_vector_type(4))) float f32x4;

__device__ __forceinline__ ushort f2bf(float f) {
  union { float f; uint32_t i; } v; v.f = f;
  uint32_t x = v.i;
  return (ushort)((x + 0x7fffu + ((x >> 16) & 1u)) >> 16);  // RNE
}

__device__ __forceinline__ void gload_lds16(const void* g, void* l) {
  __builtin_amdgcn_global_load_lds(
      (const __attribute__((address_space(1))) uint32_t*)g,
      (__attribute__((address_space(3))) uint32_t*)l,
      16, 0, 0);
}

__device__ __forceinline__ int expert_of_row(const int* __restrict__ gs, int row) {
  int cum = 0, e = 0;
#pragma unroll
  for (int i = 0; i < NE; ++i) { if (row >= cum) e = i; cum += gs[i]; }
  return e;
}

// ---- k_prepA: lora_A -> Aoct[e][ko][c][8], scale folded. 256 blocks. ----
__global__ __launch_bounds__(256) void k_prepA(
    const float* __restrict__ lora_A, const float* __restrict__ lora_scaling,
    ushort* __restrict__ Aoct) {
  const int bid = blockIdx.x;
  const int tid = threadIdx.x;
  int u = bid * 4 + (tid >> 6);         // 0..1023 = e*128+ko
  int e = u >> 7, ko = u & 127;
  int c = tid & 63;
  int a = c >> 4, r = c & 15;
  float s = lora_scaling[a];
  ushort o8[8];
#pragma unroll
  for (int j = 0; j < 8; ++j) {
    float v = lora_A[((size_t)(a * NE + e) * DIN + ko * 8 + j) * RK + r];
    o8[j] = f2bf(s * v);
  }
  *(uint4*)(Aoct + ((size_t)((e * 128 + ko) * 64 + c)) * 8) = *(const uint4*)o8;
}

// ---- k_pv ----
// blocks [0,512)     : V-blocks, 16-row tiles, 4 K-tiles per stage
// blocks [512,1536)  : W -> Boct[e][ko<128][n][8]
// blocks [1536,1600) : lora_B -> Boct[e][128+o][n][8]
__global__ __launch_bounds__(256) void k_pv(
    const float* __restrict__ x, ushort* __restrict__ vs,
    const ushort* __restrict__ Aoct,
    const float* __restrict__ weight, const float* __restrict__ lora_B,
    ushort* __restrict__ Boct,
    const int* __restrict__ gs, const int* __restrict__ adapter_idx) {
  __shared__ ushort As2[4 * 16 * 64];     // 8 KB  (4 K-tiles x 16 rows x 64)
  __shared__ ushort Bs2[4 * 8 * 64 * 8];  // 32 KB (4 K-tiles x 8 octs)

  const int bid = blockIdx.x;
  const int tid = threadIdx.x;

  if (bid < 512) {
    // ======== V: rows [vb*16, +16), V = x @ Aoct[e], masked -> vs ========
    const int vb = (bid & 7) * 64 + (bid >> 3);   // xcd k -> expert k
    const int lane = tid & 63;
    const int wave = tid >> 6;
    const int rows0 = vb * 16;
    const int e = expert_of_row(gs, rows0);
    const ushort* aoct = Aoct + (size_t)e * 128 * 64 * 8;

    const int row = tid >> 4;           // 0..15
    const int seg = tid & 15;           // 16 floats each (64 B contiguous)
    const int r7 = row & 7;
    const int t4 = seg >> 2;            // K-tile within the 4-batch
    const int c0 = (seg & 3) * 2;       // first 8-elem chunk within tile

    f32x4 acc = (f32x4){0.f, 0.f, 0.f, 0.f};

    for (int it = 0; it < 4; ++it) {
      // B: 8 async LDS loads/wave (4 tiles x 2 octs each)
#pragma unroll
      for (int i = 0; i < 8; ++i) {
        int t = i >> 1;
        int o = wave * 2 + (i & 1);               // oct 0..7 across 4 waves
        const ushort* src = aoct + ((size_t)((it * 4 + t) * 8 + o) * 64 + lane) * 8;
        gload_lds16(src, &Bs2[((t * 8 + o) * 64) * 8]);
      }

      // A: 16 fp32 (64 B contiguous) -> 16 bf16 -> swizzled LDS (no global store)
      const float* srcx = x + (size_t)(rows0 + row) * DIN + it * 256 + seg * 16;
      float4 q0 = ((const float4*)srcx)[0];
      float4 q1 = ((const float4*)srcx)[1];
      float4 q2 = ((const float4*)srcx)[2];
      float4 q3 = ((const float4*)srcx)[3];
      ushort o16[16];
      o16[0]  = f2bf(q0.x); o16[1]  = f2bf(q0.y); o16[2]  = f2bf(q0.z); o16[3]  = f2bf(q0.w);
      o16[4]  = f2bf(q1.x); o16[5]  = f2bf(q1.y); o16[6]  = f2bf(q1.z); o16[7]  = f2bf(q1.w);
      o16[8]  = f2bf(q2.x); o16[9]  = f2bf(q2.y); o16[10] = f2bf(q2.z); o16[11] = f2bf(q2.w);
      o16[12] = f2bf(q3.x); o16[13] = f2bf(q3.y); o16[14] = f2bf(q3.z); o16[15] = f2bf(q3.w);

      *(uint4*)&As2[(t4 * 16 + row) * 64 + ((c0 ^ r7) * 8)]       = ((const uint4*)o16)[0];
      *(uint4*)&As2[(t4 * 16 + row) * 64 + (((c0 + 1) ^ r7) * 8)] = ((const uint4*)o16)[1];

      __syncthreads();

      int m = lane & 15;
#pragma unroll
      for (int t = 0; t < 4; ++t) {
#pragma unroll
        for (int h = 0; h < 2; ++h) {
          int kblk = h * 4 + (lane >> 4);
          short8 af = *(const short8*)&As2[(t * 16 + m) * 64 + (kblk ^ (m & 7)) * 8];
          short8 bfv = *(const short8*)&Bs2[((t * 8 + kblk) * 64 + wave * 16 + m) * 8];
          acc = __builtin_amdgcn_mfma_f32_16x16x32_bf16(af, bfv, acc, 0, 0, 0);
        }
      }
      __syncthreads();
    }

    // epilogue: this wave owns V cols [wave*16, +16) -> adapter slot = wave
#pragma unroll
    for (int i = 0; i < 4; ++i) {
      int grow = rows0 + (lane >> 4) * 4 + i;
      int a_row = adapter_idx[grow];
      float val = (a_row == wave) ? acc[i] : 0.f;
      vs[(size_t)grow * 64 + wave * 16 + (lane & 15)] = f2bf(val);
    }
  } else {
    // ======== Boct pack ========
    int e, ko;
    const float* srcbase = nullptr;
    if (bid < 1536) {                     // W rows
      int u = bid - 512;                  // 0..1023
      e = u >> 7; ko = u & 127;
      srcbase = weight + (size_t)e * DIN * DOUT + (size_t)(ko * 8) * DOUT;
    } else {                              // lora_B rows
      int u = bid - 1536;                 // 0..63
      e = u >> 3; int o = u & 7; ko = 128 + o;
    }
    int n4 = tid * 4;
    float v[8][4];
    if (bid < 1536) {
#pragma unroll
      for (int j = 0; j < 8; ++j) {
        float4 q = *(const float4*)(srcbase + (size_t)j * DOUT + n4);
        v[j][0] = q.x; v[j][1] = q.y; v[j][2] = q.z; v[j][3] = q.w;
      }
    } else {
      int o = ko - 128;
#pragma unroll
      for (int j = 0; j < 8; ++j) {
        int kv = o * 8 + j;
        int a = kv >> 4, r = kv & 15;
        float4 q = *(const float4*)(lora_B + (size_t)((a * NE + e) * RK + r) * DOUT + n4);
        v[j][0] = q.x; v[j][1] = q.y; v[j][2] = q.z; v[j][3] = q.w;
      }
    }
    ushort* dst = Boct + ((size_t)(e * NOCT + ko) * DOUT + n4) * 8;
#pragma unroll
    for (int i = 0; i < 4; ++i) {
      ushort o8[8];
#pragma unroll
      for (int j = 0; j < 8; ++j) o8[j] = f2bf(v[j][i]);
      *(uint4*)(dst + i * 8) = *(const uint4*)o8;
    }
  }
}

// ---- k_gemm2: out[128x128] = [x|V](128 x 1088) @ Boct[e](1088 x 128) ----
// kt=0..15: A reg-staged from x fp32 (cvt + XOR-swizzled ds_write).
// kt=16   : A = V slice via gload_lds. B via gload_lds throughout.
__global__ __launch_bounds__(256) void k_gemm2(
    const float* __restrict__ x, const ushort* __restrict__ vs,
    const ushort* __restrict__ Boct,
    const int* __restrict__ gs, float* __restrict__ out) {
  __shared__ ushort As[128 * 64];      // 16 KB
  __shared__ ushort Bs[8 * 128 * 8];   // 16 KB

  const int tid = threadIdx.x;
  const int lane = tid & 63;
  const int wave = tid >> 6;
  const int wm = wave >> 1, wn = wave & 1;

  const int bid = blockIdx.x;                 // 0..511
  const int swz = (bid & 7) * 64 + (bid >> 3);  // bijective (512 % 8 == 0)
  const int row0 = (swz >> 3) * 128;
  const int n0 = (swz & 7) * 128;
  const int e = expert_of_row(gs, row0);
  const ushort* boct = Boct + (size_t)e * NOCT * DOUT * 8;

  const int xrow = tid >> 1;            // 0..127 (A-stage mapping)
  const int xseg = tid & 1;             // 32 floats each (128 B contiguous)
  const int xr7 = xrow & 7;

  f32x4 acc[4][4];
#pragma unroll
  for (int mi = 0; mi < 4; ++mi)
#pragma unroll
    for (int ni = 0; ni < 4; ++ni) acc[mi][ni] = (f32x4){0.f, 0.f, 0.f, 0.f};

  const int r8 = lane >> 3;
  const int c8s = (lane & 7) ^ r8;              // swizzled source chunk (V tail)

  for (int kt = 0; kt < 16; ++kt) {
    // A: 8 float4 from x (issued first, consumed after B-gload issue)
    const float* srcx = x + (size_t)(row0 + xrow) * DIN + kt * 64 + xseg * 32;
    float4 q[8];
#pragma unroll
    for (int j = 0; j < 8; ++j) q[j] = ((const float4*)srcx)[j];

    // B: 4 gload_lds/wave: unit = wave*4+rd -> oct o=unit>>1, half hf=unit&1
#pragma unroll
    for (int rd = 0; rd < 4; ++rd) {
      int u = wave * 4 + rd;
      int o = u >> 1, hf = u & 1;
      const ushort* src = boct + ((size_t)(kt * 8 + o) * DOUT + n0 + hf * 64 + lane) * 8;
      gload_lds16(src, &Bs[(o * 128 + hf * 64) * 8]);
    }

    // cvt + XOR-swizzled ds_write (4 octs/thread)
#pragma unroll
    for (int i = 0; i < 4; ++i) {
      ushort o8[8];
#pragma unroll
      for (int j = 0; j < 8; ++j)
        o8[j] = f2bf(((const float*)&q[i * 2 + (j >> 2)])[j & 3]);
      int c = xseg * 4 + i;
      *(uint4*)&As[xrow * 64 + ((c ^ xr7) * 8)] = *(const uint4*)o8;
    }
    __syncthreads();

#pragma unroll
    for (int h = 0; h < 2; ++h) {
      int kblk = h * 4 + (lane >> 4);
      short8 af[4], bfv[4];
#pragma unroll
      for (int mi = 0; mi < 4; ++mi) {
        int m = wm * 64 + mi * 16 + (lane & 15);
        af[mi] = *(const short8*)&As[m * 64 + (kblk ^ (m & 7)) * 8];
      }
#pragma unroll
      for (int ni = 0; ni < 4; ++ni) {
        int n = wn * 64 + ni * 16 + (lane & 15);
        bfv[ni] = *(const short8*)&Bs[(kblk * 128 + n) * 8];
      }
#pragma unroll
      for (int mi = 0; mi < 4; ++mi)
#pragma unroll
        for (int ni = 0; ni < 4; ++ni)
          acc[mi][ni] = __builtin_amdgcn_mfma_f32_16x16x32_bf16(
              af[mi], bfv[ni], acc[mi][ni], 0, 0, 0);
    }
    __syncthreads();
  }

  // ---- V tail (kt = 16): A = vs slice via gload_lds, B octs 128..135 ----
  {
#pragma unroll
    for (int rd = 0; rd < 4; ++rd) {
      int r = wave * 32 + rd * 8 + r8;
      const ushort* src = vs + (size_t)(row0 + r) * 64 + c8s * 8;
      gload_lds16(src, &As[(wave * 32 + rd * 8) * 64]);
    }
#pragma unroll
    for (int rd = 0; rd < 4; ++rd) {
      int u = wave * 4 + rd;
      int o = u >> 1, hf = u & 1;
      const ushort* src = boct + ((size_t)(16 * 8 + o) * DOUT + n0 + hf * 64 + lane) * 8;
      gload_lds16(src, &Bs[(o * 128 + hf * 64) * 8]);
    }
    __syncthreads();

#pragma unroll
    for (int h = 0; h < 2; ++h) {
      int kblk = h * 4 + (lane >> 4);
      short8 af[4], bfv[4];
#pragma unroll
      for (int mi = 0; mi < 4; ++mi) {
        int m = wm * 64 + mi * 16 + (lane & 15);
        af[mi] = *(const short8*)&As[m * 64 + (kblk ^ (m & 7)) * 8];
      }
#pragma unroll
      for (int ni = 0; ni < 4; ++ni) {
        int n = wn * 64 + ni * 16 + (lane & 15);
        bfv[ni] = *(const short8*)&Bs[(kblk * 128 + n) * 8];
      }
#pragma unroll
      for (int mi = 0; mi < 4; ++mi)
#pragma unroll
        for (int ni = 0; ni < 4; ++ni)
          acc[mi][ni] = __builtin_amdgcn_mfma_f32_16x16x32_bf16(
              af[mi], bfv[ni], acc[mi][ni], 0, 0, 0);
    }
  }

  // epilogue: C layout col=lane&15, row=(lane>>4)*4+reg
#pragma unroll
  for (int mi = 0; mi < 4; ++mi) {
#pragma unroll
    for (int ni = 0; ni < 4; ++ni) {
      int col = n0 + wn * 64 + ni * 16 + (lane & 15);
#pragma unroll
      for (int i = 0; i < 4; ++i) {
        int r = row0 + wm * 64 + mi * 16 + (lane >> 4) * 4 + i;
        out[(size_t)r * DOUT + col] = acc[mi][ni][i];
      }
    }
  }
}

extern "C" void kernel_launch(void* const* d_in, const int* in_sizes, int n_in,
                              void* d_out, int out_size, void* d_ws, size_t ws_size,
                              hipStream_t stream) {
  const float* x            = (const float*)d_in[0];
  const float* weight       = (const float*)d_in[1];
  const float* lora_A       = (const float*)d_in[2];
  const float* lora_B       = (const float*)d_in[3];
  const float* lora_scaling = (const float*)d_in[4];
  const int*   group_sizes  = (const int*)d_in[5];
  const int*   adapter_idx  = (const int*)d_in[6];
  float* out = (float*)d_out;

  const size_t sz_vs   = (size_t)T_TOK * 64 * 2;                // 1 MB
  const size_t sz_boct = (size_t)NE * NOCT * DOUT * 8 * 2;      // 17.8 MB
  ushort* vsb  = (ushort*)d_ws;
  ushort* boct = (ushort*)((char*)d_ws + sz_vs);
  ushort* aoct = (ushort*)((char*)d_ws + sz_vs + sz_boct);      // 1 MB

  k_prepA<<<256, 256, 0, stream>>>(lora_A, lora_scaling, aoct);
  k_pv<<<1600, 256, 0, stream>>>(x, vsb, aoct, weight, lora_B, boct,
                                 group_sizes, adapter_idx);
  k_gemm2<<<512, 256, 0, stream>>>(x, vsb, boct, group_sizes, out);
}

// Round 6
// 166.955 us; speedup vs baseline: 1.0508x; 1.0508x over previous
//
#include <hip/hip_runtime.h>
#include <hip/hip_bf16.h>
#include <stdint.h>

// LoRAExpert: out = ragged_dot(x, W, groups) + scale[a] * ((x @ A[a,e]) @ B[a,e])
// T=8192, D_IN=D_OUT=1024, E=8 (equal groups of 1024), A=4 adapters, R=16.
// Inputs fp32, output fp32. ws = 256 MiB.
//
// Round 11: revert k_gemm to the verified R9 form (R10 post-mortem: fp32
// reg-staging put 8x-redundant cvt on the MFMA critical path, +26us).
// Rebuild the producer as ONE barrier-free kernel:
//   k_main : blocks [0,512)     : V-blocks -- NO LDS, NO barriers. A-frags
//            loaded per-lane from x fp32 (2xfloat4+cvt), B-frags per-lane
//            from lora_A fp32 (scale folded in-register; values provably
//            identical to the old Aoct path: a=wave, r=lane&15, the XOR
//            swizzle cancels). XCD-swizzled so expert e's lora_A slice
//            (256 KB) is L2-resident on xcd e. V -> xp[:, 1024:1088].
//            blocks [512,1536)  : x -> bf16 xp[:, :1024] (R5 coalesced pattern)
//            blocks [1536,2560) : W -> Boct[e][ko<128][n][8]
//            blocks [2560,2624) : lora_B -> Boct[e][128+o][n][8]
//            (k_prepA and the Aoct tensor are deleted.)
//   k_gemm : out = xp(K=1088) @ Boct[e]. Verbatim R9: 128x128, BK=64,
//            gload_lds w16, XOR-swizzled A LDS, XCD-aware 1-D swizzle.

#define T_TOK 8192
#define DIN   1024
#define DOUT  1024
#define NE    8
#define NA    4
#define RK    16
#define KEXT  1088      // 1024 + NA*RK
#define NOCT  136       // KEXT/8

typedef __attribute__((ext_vector_type(8))) short short8;
typedef __attribute__((ext_vector_type(4))) float f32x4;

__device__ __forceinline__ ushort f2bf(float f) {
  union { float f; uint32_t i; } v; v.f = f;
  uint32_t x = v.i;
  return (ushort)((x + 0x7fffu + ((x >> 16) & 1u)) >> 16);  // RNE
}

__device__ __forceinline__ void gload_lds16(const void* g, void* l) {
  __builtin_amdgcn_global_load_lds(
      (const __attribute__((address_space(1))) uint32_t*)g,
      (__attribute__((address_space(3))) uint32_t*)l,
      16, 0, 0);
}

__device__ __forceinline__ int expert_of_row(const int* __restrict__ gs, int row) {
  int cum = 0, e = 0;
#pragma unroll
  for (int i = 0; i < NE; ++i) { if (row >= cum) e = i; cum += gs[i]; }
  return e;
}

// ---- k_main ----
// blocks [0,512)     : V-blocks (LDS-free, barrier-free)
// blocks [512,1536)  : x -> xp[:, :1024]
// blocks [1536,2560) : W -> Boct
// blocks [2560,2624) : lora_B -> Boct
__global__ __launch_bounds__(256) void k_main(
    const float* __restrict__ x, ushort* __restrict__ xp,
    const float* __restrict__ lora_A, const float* __restrict__ lora_scaling,
    const float* __restrict__ weight, const float* __restrict__ lora_B,
    ushort* __restrict__ Boct,
    const int* __restrict__ gs, const int* __restrict__ adapter_idx) {
  const int bid = blockIdx.x;
  const int tid = threadIdx.x;

  if (bid < 512) {
    // ======== V: rows [vb*16, +16), V = x @ (s*lora_A[e]) -> xp[:,1024:] ====
    const int vb = (bid & 7) * 64 + (bid >> 3);   // xcd k <- expert k
    const int lane = tid & 63;
    const int wave = tid >> 6;                    // = adapter a
    const int rows0 = vb * 16;
    const int e = expert_of_row(gs, rows0);
    const int m = lane & 15;                      // row-within-tile / r
    const int kg = lane >> 4;                     // k-group 0..3
    const float s = lora_scaling[wave];
    // lora_A[((wave*NE+e)*DIN + k)*RK + m], walked by k
    const float* la = lora_A + (size_t)(wave * NE + e) * DIN * RK + m;
    const float* xr = x + (size_t)(rows0 + m) * DIN;

    f32x4 acc = (f32x4){0.f, 0.f, 0.f, 0.f};

    for (int kt = 0; kt < 16; ++kt) {
#pragma unroll
      for (int h = 0; h < 2; ++h) {
        const int kblk = h * 4 + kg;
        const int k0 = kt * 64 + kblk * 8;
        // A-frag: x[rows0+m][k0 .. k0+8)
        float4 a0 = *(const float4*)(xr + k0);
        float4 a1 = *(const float4*)(xr + k0 + 4);
        short8 af;
        af[0] = (short)f2bf(a0.x); af[1] = (short)f2bf(a0.y);
        af[2] = (short)f2bf(a0.z); af[3] = (short)f2bf(a0.w);
        af[4] = (short)f2bf(a1.x); af[5] = (short)f2bf(a1.y);
        af[6] = (short)f2bf(a1.z); af[7] = (short)f2bf(a1.w);
        // B-frag: s * lora_A[((wave*8+e)*1024 + k0+j)*16 + m]
        short8 bf;
#pragma unroll
        for (int j = 0; j < 8; ++j)
          bf[j] = (short)f2bf(s * la[(size_t)(k0 + j) * RK]);
        acc = __builtin_amdgcn_mfma_f32_16x16x32_bf16(af, bf, acc, 0, 0, 0);
      }
    }

    // epilogue: wave owns V cols [wave*16,+16) -> adapter slot = wave
#pragma unroll
    for (int i = 0; i < 4; ++i) {
      int grow = rows0 + kg * 4 + i;
      int a_row = adapter_idx[grow];
      float val = (a_row == wave) ? acc[i] : 0.f;
      xp[(size_t)grow * KEXT + DIN + wave * 16 + m] = f2bf(val);
    }
  } else if (bid < 1536) {
    // ======== pack x -> xp[:, :1024] ========
    int idx = (bid - 512) * 2048 + tid * 8;       // 8 float4 per thread
#pragma unroll
    for (int i = 0; i < 8; ++i) {
      int u = idx + i;                            // float4 index
      int row = u >> 8;                           // 256 float4 per row
      int c4 = u & 255;
      float4 v = *(const float4*)(x + (size_t)row * DIN + c4 * 4);
      ushort4 b;
      b.x = f2bf(v.x); b.y = f2bf(v.y); b.z = f2bf(v.z); b.w = f2bf(v.w);
      *(ushort4*)(xp + (size_t)row * KEXT + c4 * 4) = b;
    }
  } else {
    // ======== Boct pack ========
    int e, ko;
    const float* srcbase = nullptr;
    if (bid < 2560) {                     // W rows
      int u = bid - 1536;                 // 0..1023
      e = u >> 7; ko = u & 127;
      srcbase = weight + (size_t)e * DIN * DOUT + (size_t)(ko * 8) * DOUT;
    } else {                              // lora_B rows
      int u = bid - 2560;                 // 0..63
      e = u >> 3; int o = u & 7; ko = 128 + o;
    }
    int n4 = tid * 4;
    float v[8][4];
    if (bid < 2560) {
#pragma unroll
      for (int j = 0; j < 8; ++j) {
        float4 q = *(const float4*)(srcbase + (size_t)j * DOUT + n4);
        v[j][0] = q.x; v[j][1] = q.y; v[j][2] = q.z; v[j][3] = q.w;
      }
    } else {
      int o = ko - 128;
#pragma unroll
      for (int j = 0; j < 8; ++j) {
        int kv = o * 8 + j;
        int a = kv >> 4, r = kv & 15;
        float4 q = *(const float4*)(lora_B + (size_t)((a * NE + e) * RK + r) * DOUT + n4);
        v[j][0] = q.x; v[j][1] = q.y; v[j][2] = q.z; v[j][3] = q.w;
      }
    }
    ushort* dst = Boct + ((size_t)(e * NOCT + ko) * DOUT + n4) * 8;
#pragma unroll
    for (int i = 0; i < 4; ++i) {
      ushort o8[8];
#pragma unroll
      for (int j = 0; j < 8; ++j) o8[j] = f2bf(v[j][i]);
      *(uint4*)(dst + i * 8) = *(const uint4*)o8;
    }
  }
}

// ---- k_gemm: out[128x128] = xp(128 x 1088) @ Boct[e](1088 x 128) ----
// BK=64, 17 iters. A LDS XOR-swizzled. 1-D grid 512 with XCD swizzle.
// (verbatim R9 -- verified at 156 us)
__global__ __launch_bounds__(256) void k_gemm(
    const ushort* __restrict__ xp, const ushort* __restrict__ Boct,
    const int* __restrict__ gs, float* __restrict__ out) {
  __shared__ ushort As[128 * 64];      // 16 KB
  __shared__ ushort Bs[8 * 128 * 8];   // 16 KB

  const int tid = threadIdx.x;
  const int lane = tid & 63;
  const int wave = tid >> 6;
  const int wm = wave >> 1, wn = wave & 1;

  const int bid = blockIdx.x;                 // 0..511
  const int swz = (bid & 7) * 64 + (bid >> 3);  // bijective (512 % 8 == 0)
  const int row0 = (swz >> 3) * 128;
  const int n0 = (swz & 7) * 128;
  const int e = expert_of_row(gs, row0);
  const ushort* boct = Boct + (size_t)e * NOCT * DOUT * 8;

  f32x4 acc[4][4];
#pragma unroll
  for (int mi = 0; mi < 4; ++mi)
#pragma unroll
    for (int ni = 0; ni < 4; ++ni) acc[mi][ni] = (f32x4){0.f, 0.f, 0.f, 0.f};

  const int r8 = lane >> 3;
  const int c8s = (lane & 7) ^ r8;              // swizzled source chunk

  for (int kt = 0; kt < 17; ++kt) {
    // A: 4 calls/wave, 8 rows x 8 chunks each (swizzled)
#pragma unroll
    for (int rd = 0; rd < 4; ++rd) {
      int r = wave * 32 + rd * 8 + r8;
      const ushort* src = xp + (size_t)(row0 + r) * KEXT + kt * 64 + c8s * 8;
      gload_lds16(src, &As[(wave * 32 + rd * 8) * 64]);
    }
    // B: 4 calls/wave: unit = wave*4+rd -> oct o=unit>>1, half hf=unit&1
#pragma unroll
    for (int rd = 0; rd < 4; ++rd) {
      int u = wave * 4 + rd;
      int o = u >> 1, hf = u & 1;
      const ushort* src = boct + ((size_t)(kt * 8 + o) * DOUT + n0 + hf * 64 + lane) * 8;
      gload_lds16(src, &Bs[(o * 128 + hf * 64) * 8]);
    }
    __syncthreads();

#pragma unroll
    for (int h = 0; h < 2; ++h) {
      int kblk = h * 4 + (lane >> 4);
      short8 af[4], bfv[4];
#pragma unroll
      for (int mi = 0; mi < 4; ++mi) {
        int m = wm * 64 + mi * 16 + (lane & 15);
        af[mi] = *(const short8*)&As[m * 64 + (kblk ^ (m & 7)) * 8];
      }
#pragma unroll
      for (int ni = 0; ni < 4; ++ni) {
        int n = wn * 64 + ni * 16 + (lane & 15);
        bfv[ni] = *(const short8*)&Bs[(kblk * 128 + n) * 8];
      }
#pragma unroll
      for (int mi = 0; mi < 4; ++mi)
#pragma unroll
        for (int ni = 0; ni < 4; ++ni)
          acc[mi][ni] = __builtin_amdgcn_mfma_f32_16x16x32_bf16(
              af[mi], bfv[ni], acc[mi][ni], 0, 0, 0);
    }
    __syncthreads();
  }

  // epilogue: C layout col=lane&15, row=(lane>>4)*4+reg
#pragma unroll
  for (int mi = 0; mi < 4; ++mi) {
#pragma unroll
    for (int ni = 0; ni < 4; ++ni) {
      int col = n0 + wn * 64 + ni * 16 + (lane & 15);
#pragma unroll
      for (int i = 0; i < 4; ++i) {
        int r = row0 + wm * 64 + mi * 16 + (lane >> 4) * 4 + i;
        out[(size_t)r * DOUT + col] = acc[mi][ni][i];
      }
    }
  }
}

extern "C" void kernel_launch(void* const* d_in, const int* in_sizes, int n_in,
                              void* d_out, int out_size, void* d_ws, size_t ws_size,
                              hipStream_t stream) {
  const float* x            = (const float*)d_in[0];
  const float* weight       = (const float*)d_in[1];
  const float* lora_A       = (const float*)d_in[2];
  const float* lora_B       = (const float*)d_in[3];
  const float* lora_scaling = (const float*)d_in[4];
  const int*   group_sizes  = (const int*)d_in[5];
  const int*   adapter_idx  = (const int*)d_in[6];
  float* out = (float*)d_out;

  const size_t sz_xp = (size_t)T_TOK * KEXT * 2;                // 17.8 MB
  ushort* xp   = (ushort*)d_ws;
  ushort* boct = (ushort*)((char*)d_ws + sz_xp);                // 17.8 MB

  k_main<<<2624, 256, 0, stream>>>(x, xp, lora_A, lora_scaling,
                                   weight, lora_B, boct,
                                   group_sizes, adapter_idx);
  k_gemm<<<512, 256, 0, stream>>>(xp, boct, group_sizes, out);
}

// Round 7
// 152.684 us; speedup vs baseline: 1.1490x; 1.0935x over previous
//
#include <hip/hip_runtime.h>
#include <hip/hip_bf16.h>
#include <stdint.h>

// LoRAExpert: out = ragged_dot(x, W, groups) + scale[a] * ((x @ A[a,e]) @ B[a,e])
// T=8192, D_IN=D_OUT=1024, E=8 (equal groups of 1024), A=4 adapters, R=16.
// Inputs fp32, output fp32. ws = 256 MiB.
//
// Round 12: producer reverted to verified R9 form (R11 post-mortem: LDS-free
// V path made 4x-redundant x reads, +14us). k_gemm: double K-step --
// stage TWO BK=64 tiles per barrier pair (As[2]/Bs[2], 64KB LDS), compute
// both. Barrier drains 34->18, 16 gloads/wave in flight (was 8), 32 MFMAs
// per barrier (was 16). Addressing/swizzle/fragments byte-identical.
//   k_prepA : lora_A -> Aoct (scale folded). 256 blocks.
//   k_main  : blocks [0,512)    : xva, 16-row tiles, 4-tile K-batching,
//                                 packs x -> xp[:, :1024] inline, V ->
//                                 xp[:, 1024:1088] (adapter-masked).
//             blocks [512,1600) : W/lora_B -> Boct pack.
//   k_gemm  : out = xp(K=1088) @ Boct[e]. 128x128, double K-step,
//             XOR-swizzled A LDS, gload_lds w16, XCD-aware 1-D swizzle.

#define T_TOK 8192
#define DIN   1024
#define DOUT  1024
#define NE    8
#define NA    4
#define RK    16
#define KEXT  1088      // 1024 + NA*RK
#define NOCT  136       // KEXT/8

typedef __attribute__((ext_vector_type(8))) short short8;
typedef __attribute__((ext_vector_type(4))) float f32x4;

__device__ __forceinline__ ushort f2bf(float f) {
  union { float f; uint32_t i; } v; v.f = f;
  uint32_t x = v.i;
  return (ushort)((x + 0x7fffu + ((x >> 16) & 1u)) >> 16);  // RNE
}

__device__ __forceinline__ void gload_lds16(const void* g, void* l) {
  __builtin_amdgcn_global_load_lds(
      (const __attribute__((address_space(1))) uint32_t*)g,
      (__attribute__((address_space(3))) uint32_t*)l,
      16, 0, 0);
}

__device__ __forceinline__ int expert_of_row(const int* __restrict__ gs, int row) {
  int cum = 0, e = 0;
#pragma unroll
  for (int i = 0; i < NE; ++i) { if (row >= cum) e = i; cum += gs[i]; }
  return e;
}

// ---- k_prepA: lora_A -> Aoct[e][ko][c][8], scale folded. 256 blocks. ----
__global__ __launch_bounds__(256) void k_prepA(
    const float* __restrict__ lora_A, const float* __restrict__ lora_scaling,
    ushort* __restrict__ Aoct) {
  const int bid = blockIdx.x;
  const int tid = threadIdx.x;
  int u = bid * 4 + (tid >> 6);         // 0..1023 = e*128+ko
  int e = u >> 7, ko = u & 127;
  int c = tid & 63;
  int a = c >> 4, r = c & 15;
  float s = lora_scaling[a];
  ushort o8[8];
#pragma unroll
  for (int j = 0; j < 8; ++j) {
    float v = lora_A[((size_t)(a * NE + e) * DIN + ko * 8 + j) * RK + r];
    o8[j] = f2bf(s * v);
  }
  *(uint4*)(Aoct + ((size_t)((e * 128 + ko) * 64 + c)) * 8) = *(const uint4*)o8;
}

// ---- k_main ----
// blocks [0,512)     : xva, 16-row tiles, 4 K-tiles per stage
// blocks [512,1536)  : W -> Boct[e][ko<128][n][8]
// blocks [1536,1600) : lora_B -> Boct[e][128+o][n][8]
__global__ __launch_bounds__(256) void k_main(
    const float* __restrict__ x, ushort* __restrict__ xp,
    const ushort* __restrict__ Aoct,
    const float* __restrict__ weight, const float* __restrict__ lora_B,
    ushort* __restrict__ Boct,
    const int* __restrict__ gs, const int* __restrict__ adapter_idx) {
  __shared__ ushort As2[4 * 16 * 64];     // 8 KB  (4 K-tiles x 16 rows x 64)
  __shared__ ushort Bs2[4 * 8 * 64 * 8];  // 32 KB (4 K-tiles x 8 octs)

  const int bid = blockIdx.x;
  const int tid = threadIdx.x;

  if (bid < 512) {
    // ======== xva: pack x rows [bid*16, +16) and compute V ========
    const int lane = tid & 63;
    const int wave = tid >> 6;
    const int rows0 = bid * 16;
    const int e = expert_of_row(gs, rows0);
    const ushort* aoct = Aoct + (size_t)e * 128 * 64 * 8;

    const int row = tid >> 4;           // 0..15
    const int seg = tid & 15;           // 16 floats each (64 B contiguous)
    const int r7 = row & 7;
    const int t4 = seg >> 2;            // K-tile within the 4-batch
    const int c0 = (seg & 3) * 2;       // first 8-elem chunk within tile

    f32x4 acc = (f32x4){0.f, 0.f, 0.f, 0.f};

    for (int it = 0; it < 4; ++it) {
      // B: 8 async LDS loads/wave (4 tiles x 2 octs each)
#pragma unroll
      for (int i = 0; i < 8; ++i) {
        int t = i >> 1;
        int o = wave * 2 + (i & 1);               // oct 0..7 across 4 waves
        const ushort* src = aoct + ((size_t)((it * 4 + t) * 8 + o) * 64 + lane) * 8;
        gload_lds16(src, &Bs2[((t * 8 + o) * 64) * 8]);
      }

      // A: 16 fp32 (64 B contiguous) -> 16 bf16 -> global xp + swizzled LDS
      const float* srcx = x + (size_t)(rows0 + row) * DIN + it * 256 + seg * 16;
      float4 q0 = ((const float4*)srcx)[0];
      float4 q1 = ((const float4*)srcx)[1];
      float4 q2 = ((const float4*)srcx)[2];
      float4 q3 = ((const float4*)srcx)[3];
      ushort o16[16];
      o16[0]  = f2bf(q0.x); o16[1]  = f2bf(q0.y); o16[2]  = f2bf(q0.z); o16[3]  = f2bf(q0.w);
      o16[4]  = f2bf(q1.x); o16[5]  = f2bf(q1.y); o16[6]  = f2bf(q1.z); o16[7]  = f2bf(q1.w);
      o16[8]  = f2bf(q2.x); o16[9]  = f2bf(q2.y); o16[10] = f2bf(q2.z); o16[11] = f2bf(q2.w);
      o16[12] = f2bf(q3.x); o16[13] = f2bf(q3.y); o16[14] = f2bf(q3.z); o16[15] = f2bf(q3.w);

      ushort* dstg = xp + (size_t)(rows0 + row) * KEXT + it * 256 + seg * 16;
      *(uint4*)(dstg)     = ((const uint4*)o16)[0];
      *(uint4*)(dstg + 8) = ((const uint4*)o16)[1];

      *(uint4*)&As2[(t4 * 16 + row) * 64 + ((c0 ^ r7) * 8)]       = ((const uint4*)o16)[0];
      *(uint4*)&As2[(t4 * 16 + row) * 64 + (((c0 + 1) ^ r7) * 8)] = ((const uint4*)o16)[1];

      __syncthreads();

      int m = lane & 15;
#pragma unroll
      for (int t = 0; t < 4; ++t) {
#pragma unroll
        for (int h = 0; h < 2; ++h) {
          int kblk = h * 4 + (lane >> 4);
          short8 af = *(const short8*)&As2[(t * 16 + m) * 64 + (kblk ^ (m & 7)) * 8];
          short8 bfv = *(const short8*)&Bs2[((t * 8 + kblk) * 64 + wave * 16 + m) * 8];
          acc = __builtin_amdgcn_mfma_f32_16x16x32_bf16(af, bfv, acc, 0, 0, 0);
        }
      }
      __syncthreads();
    }

    // epilogue: this wave owns V cols [wave*16, +16) -> adapter slot = wave
#pragma unroll
    for (int i = 0; i < 4; ++i) {
      int grow = rows0 + (lane >> 4) * 4 + i;
      int a_row = adapter_idx[grow];
      float val = (a_row == wave) ? acc[i] : 0.f;
      xp[(size_t)grow * KEXT + DIN + wave * 16 + (lane & 15)] = f2bf(val);
    }
  } else {
    // ======== Boct pack ========
    int e, ko;
    const float* srcbase = nullptr;
    if (bid < 1536) {                     // W rows
      int u = bid - 512;                  // 0..1023
      e = u >> 7; ko = u & 127;
      srcbase = weight + (size_t)e * DIN * DOUT + (size_t)(ko * 8) * DOUT;
    } else {                              // lora_B rows
      int u = bid - 1536;                 // 0..63
      e = u >> 3; int o = u & 7; ko = 128 + o;
    }
    int n4 = tid * 4;
    float v[8][4];
    if (bid < 1536) {
#pragma unroll
      for (int j = 0; j < 8; ++j) {
        float4 q = *(const float4*)(srcbase + (size_t)j * DOUT + n4);
        v[j][0] = q.x; v[j][1] = q.y; v[j][2] = q.z; v[j][3] = q.w;
      }
    } else {
      int o = ko - 128;
#pragma unroll
      for (int j = 0; j < 8; ++j) {
        int kv = o * 8 + j;
        int a = kv >> 4, r = kv & 15;
        float4 q = *(const float4*)(lora_B + (size_t)((a * NE + e) * RK + r) * DOUT + n4);
        v[j][0] = q.x; v[j][1] = q.y; v[j][2] = q.z; v[j][3] = q.w;
      }
    }
    ushort* dst = Boct + ((size_t)(e * NOCT + ko) * DOUT + n4) * 8;
#pragma unroll
    for (int i = 0; i < 4; ++i) {
      ushort o8[8];
#pragma unroll
      for (int j = 0; j < 8; ++j) o8[j] = f2bf(v[j][i]);
      *(uint4*)(dst + i * 8) = *(const uint4*)o8;
    }
  }
}

// ---- k_gemm: out[128x128] = xp(128 x 1088) @ Boct[e](1088 x 128) ----
// Double K-step: stage 2 x BK=64 tiles per barrier pair (As[2]/Bs[2]),
// compute both. 9 outer iters (8 double + 1 single). XCD-aware swizzle.
__global__ __launch_bounds__(256) void k_gemm(
    const ushort* __restrict__ xp, const ushort* __restrict__ Boct,
    const int* __restrict__ gs, float* __restrict__ out) {
  __shared__ ushort As[2][128 * 64];      // 32 KB
  __shared__ ushort Bs[2][8 * 128 * 8];   // 32 KB

  const int tid = threadIdx.x;
  const int lane = tid & 63;
  const int wave = tid >> 6;
  const int wm = wave >> 1, wn = wave & 1;

  const int bid = blockIdx.x;                 // 0..511
  const int swz = (bid & 7) * 64 + (bid >> 3);  // bijective (512 % 8 == 0)
  const int row0 = (swz >> 3) * 128;
  const int n0 = (swz & 7) * 128;
  const int e = expert_of_row(gs, row0);
  const ushort* boct = Boct + (size_t)e * NOCT * DOUT * 8;

  f32x4 acc[4][4];
#pragma unroll
  for (int mi = 0; mi < 4; ++mi)
#pragma unroll
    for (int ni = 0; ni < 4; ++ni) acc[mi][ni] = (f32x4){0.f, 0.f, 0.f, 0.f};

  const int r8 = lane >> 3;
  const int c8s = (lane & 7) ^ r8;              // swizzled source chunk

  // stage one BK=64 tile (kt) into buffer hb
#define STAGE_TILE(hb, kt)                                                     \
  do {                                                                         \
    _Pragma("unroll")                                                          \
    for (int rd = 0; rd < 4; ++rd) {                                           \
      int r_ = wave * 32 + rd * 8 + r8;                                        \
      const ushort* src_ = xp + (size_t)(row0 + r_) * KEXT + (kt) * 64 + c8s * 8; \
      gload_lds16(src_, &As[hb][(wave * 32 + rd * 8) * 64]);                   \
    }                                                                          \
    _Pragma("unroll")                                                          \
    for (int rd = 0; rd < 4; ++rd) {                                           \
      int u_ = wave * 4 + rd;                                                  \
      int o_ = u_ >> 1, hf_ = u_ & 1;                                          \
      const ushort* src_ =                                                     \
          boct + ((size_t)((kt) * 8 + o_) * DOUT + n0 + hf_ * 64 + lane) * 8;  \
      gload_lds16(src_, &Bs[hb][(o_ * 128 + hf_ * 64) * 8]);                   \
    }                                                                          \
  } while (0)

  // compute one BK=64 tile from buffer hb
#define COMPUTE_TILE(hb)                                                       \
  do {                                                                         \
    _Pragma("unroll")                                                          \
    for (int h = 0; h < 2; ++h) {                                              \
      int kblk = h * 4 + (lane >> 4);                                          \
      short8 af[4], bfv[4];                                                    \
      _Pragma("unroll")                                                        \
      for (int mi = 0; mi < 4; ++mi) {                                         \
        int m_ = wm * 64 + mi * 16 + (lane & 15);                              \
        af[mi] = *(const short8*)&As[hb][m_ * 64 + (kblk ^ (m_ & 7)) * 8];     \
      }                                                                        \
      _Pragma("unroll")                                                        \
      for (int ni = 0; ni < 4; ++ni) {                                         \
        int n_ = wn * 64 + ni * 16 + (lane & 15);                              \
        bfv[ni] = *(const short8*)&Bs[hb][(kblk * 128 + n_) * 8];              \
      }                                                                        \
      _Pragma("unroll")                                                        \
      for (int mi = 0; mi < 4; ++mi)                                           \
        _Pragma("unroll")                                                      \
        for (int ni = 0; ni < 4; ++ni)                                         \
          acc[mi][ni] = __builtin_amdgcn_mfma_f32_16x16x32_bf16(               \
              af[mi], bfv[ni], acc[mi][ni], 0, 0, 0);                          \
    }                                                                          \
  } while (0)

  for (int kp = 0; kp < 8; ++kp) {
    STAGE_TILE(0, kp * 2);
    STAGE_TILE(1, kp * 2 + 1);
    __syncthreads();
    COMPUTE_TILE(0);
    COMPUTE_TILE(1);
    __syncthreads();
  }
  // tail: kt = 16
  STAGE_TILE(0, 16);
  __syncthreads();
  COMPUTE_TILE(0);

#undef STAGE_TILE
#undef COMPUTE_TILE

  // epilogue: C layout col=lane&15, row=(lane>>4)*4+reg
#pragma unroll
  for (int mi = 0; mi < 4; ++mi) {
#pragma unroll
    for (int ni = 0; ni < 4; ++ni) {
      int col = n0 + wn * 64 + ni * 16 + (lane & 15);
#pragma unroll
      for (int i = 0; i < 4; ++i) {
        int r = row0 + wm * 64 + mi * 16 + (lane >> 4) * 4 + i;
        out[(size_t)r * DOUT + col] = acc[mi][ni][i];
      }
    }
  }
}

extern "C" void kernel_launch(void* const* d_in, const int* in_sizes, int n_in,
                              void* d_out, int out_size, void* d_ws, size_t ws_size,
                              hipStream_t stream) {
  const float* x            = (const float*)d_in[0];
  const float* weight       = (const float*)d_in[1];
  const float* lora_A       = (const float*)d_in[2];
  const float* lora_B       = (const float*)d_in[3];
  const float* lora_scaling = (const float*)d_in[4];
  const int*   group_sizes  = (const int*)d_in[5];
  const int*   adapter_idx  = (const int*)d_in[6];
  float* out = (float*)d_out;

  const size_t sz_xp = (size_t)T_TOK * KEXT * 2;                // 17.8 MB
  ushort* xp   = (ushort*)d_ws;
  ushort* boct = (ushort*)((char*)d_ws + sz_xp);                // 17.8 MB
  ushort* aoct = (ushort*)((char*)d_ws + 2 * sz_xp);            // 1 MB

  k_prepA<<<256, 256, 0, stream>>>(lora_A, lora_scaling, aoct);
  k_main<<<1600, 256, 0, stream>>>(x, xp, aoct, weight, lora_B, boct,
                                   group_sizes, adapter_idx);
  k_gemm<<<512, 256, 0, stream>>>(xp, boct, group_sizes, out);
}